// Round 6
// baseline (1662.304 us; speedup 1.0000x reference)
//
#include <hip/hip_runtime.h>
#include <stdint.h>

#define T_ROWS 1024
#define NVIS   4096
#define NHID   2048
#define KGIBBS 25   // K is a static python int (25) in setup_inputs

typedef __attribute__((ext_vector_type(8))) short short8;
typedef __attribute__((ext_vector_type(16))) float f32x16;
typedef __attribute__((ext_vector_type(4))) unsigned short us4;

#define AS1CV(p) ((const __attribute__((address_space(1))) void*)(p))
#define AS3V(p)  ((__attribute__((address_space(3))) void*)(p))

__device__ inline unsigned short f2bf(float f) {
  union { float f; uint32_t u; } c; c.f = f;
  uint32_t u = c.u;
  uint32_t r = (u + 0x7FFFu + ((u >> 16) & 1u)) >> 16;
  return (unsigned short)r;
}

__device__ inline float bf2f(unsigned short s) {
  union { uint32_t u; float f; } c; c.u = ((uint32_t)s) << 16;
  return c.f;
}

// deterministic counter-based uniform in [0,1): murmur3 fmix64 of (phase, idx)
__device__ inline float rng_u(uint32_t phase, uint32_t idx) {
  uint64_t z = (((uint64_t)phase) << 42) | (uint64_t)idx;
  z ^= z >> 33; z *= 0xFF51AFD7ED558CCDULL;
  z ^= z >> 33; z *= 0xC4CEB9FE1A85EC53ULL;
  z ^= z >> 33;
  return (float)(uint32_t)(z >> 40) * (1.0f / 16777216.0f);
}

// ---------------------------------------------------------------------------
// W prep: fp32 -> bf16, plus transposed copy (so both GEMM directions are NT)
// ---------------------------------------------------------------------------
__global__ void __launch_bounds__(256) prep_w(const float* __restrict__ w,
                                              unsigned short* __restrict__ Wb,
                                              unsigned short* __restrict__ WTb)
{
  __shared__ unsigned short tile[64][72];
  const int bi  = blockIdx.x * 64;
  const int bh0 = blockIdx.y * 64;
  const int t   = threadIdx.x;
  const int rr  = t >> 4;
  const int cc  = (t & 15) * 4;
#pragma unroll
  for (int p = 0; p < 4; ++p) {
    int row = p * 16 + rr;
    const float4 v = *(const float4*)&w[(size_t)(bh0 + row) * NVIS + bi + cc];
    unsigned short b0 = f2bf(v.x), b1 = f2bf(v.y), b2 = f2bf(v.z), b3 = f2bf(v.w);
    us4 pk; pk.x = b0; pk.y = b1; pk.z = b2; pk.w = b3;
    *(us4*)&Wb[(size_t)(bh0 + row) * NVIS + bi + cc] = pk;
    tile[cc + 0][row] = b0; tile[cc + 1][row] = b1;
    tile[cc + 2][row] = b2; tile[cc + 3][row] = b3;
  }
  __syncthreads();
#pragma unroll
  for (int p = 0; p < 4; ++p) {
    int row = p * 16 + rr;
    us4 pk;
    pk.x = tile[row][cc + 0]; pk.y = tile[row][cc + 1];
    pk.z = tile[row][cc + 2]; pk.w = tile[row][cc + 3];
    *(us4*)&WTb[(size_t)(bi + row) * NHID + bh0 + cc] = pk;
  }
}

__global__ void __launch_bounds__(256) xcvt(const float* __restrict__ x,
                                            unsigned short* __restrict__ Vb)
{
  int i = blockIdx.x * 256 + threadIdx.x;
  const float4 v = ((const float4*)x)[i];
  us4 pk; pk.x = f2bf(v.x); pk.y = f2bf(v.y); pk.z = f2bf(v.z); pk.w = f2bf(v.w);
  ((us4*)Vb)[i] = pk;
}

__global__ void __launch_bounds__(256) bvdot(const unsigned short* __restrict__ V,
                                             const float* __restrict__ bv,
                                             float* __restrict__ part)
{
  float local = 0.f;
  for (int v = blockIdx.x * 256 + threadIdx.x; v < T_ROWS * NVIS / 4; v += 256 * 256) {
    int col4 = (v & (NVIS / 4 - 1)) * 4;
    us4 a = ((const us4*)V)[v];
    float4 b = *(const float4*)&bv[col4];
    local += bf2f(a.x) * b.x + bf2f(a.y) * b.y + bf2f(a.z) * b.z + bf2f(a.w) * b.w;
  }
#pragma unroll
  for (int off = 32; off > 0; off >>= 1) local += __shfl_down(local, off, 64);
  __shared__ float red[4];
  if ((threadIdx.x & 63) == 0) red[threadIdx.x >> 6] = local;
  __syncthreads();
  if (threadIdx.x == 0) part[blockIdx.x] = red[0] + red[1] + red[2] + red[3];
}

// ---------------------------------------------------------------------------
// GEMM: C[M,N] = A[M,K] * B^T, B stored [N][K]. BN=128; BM template; BK=64.
// 512 threads = 8 waves (2 M x 4 N). 32x32x16 bf16 MFMA, wave tile (BM/2)x32.
// 3-buffer LDS, stage-ahead-2, counted vmcnt; K-loop is a half-tile software
// pipeline: ds_reads for half h+1 issue before the MFMA cluster for half h
// (double-buffered fragment register sets), one barrier per K-tile.
// MODE 0: C = bernoulli(sigmoid(z + bias)) bf16 {0,1}
// MODE 1: fpart[block] = sum softplus(z + bias)
// ---------------------------------------------------------------------------
template <int MODE, int BM>
__global__ void __launch_bounds__(512, 2)
rbm_gemm(const unsigned short* __restrict__ A, int lda,
         const unsigned short* __restrict__ B, int ldb,
         const float* __restrict__ bias,
         unsigned short* __restrict__ C, int ldc,
         float* __restrict__ fpart,
         int kdim, uint32_t phase)
{
  constexpr int BK = 64;
  constexpr int MR = BM / 64;            // 32-row frags per wave (1 or 2)
  constexpr int CH = BK / 8;             // 16B chunks per LDS row (8)
  constexpr int ABYTES = BM * BK * 2;
  constexpr int BBYTES = 128 * BK * 2;
  constexpr int BUFB = ABYTES + BBYTES;
  constexpr int AJ = ABYTES / 8192;      // A loads per thread per stage
  constexpr int BJ = BBYTES / 8192;      // B loads per thread per stage
  constexpr int NL = AJ + BJ;            // loads in flight per stage (3 or 4)
  constexpr int RSTEP = 512 / CH;        // rows per j step (64)
  __shared__ __align__(16) char lds[3 * BUFB];

  const int tid  = threadIdx.x;
  const int lane = tid & 63;
  const int wv   = tid >> 6;
  const int wr   = wv >> 2;              // 0..1  (M)
  const int wc   = wv & 3;               // 0..3  (N)
  const int l31  = lane & 31;
  const int lq2  = lane >> 5;

  // XCD-chunked tile swizzle (col-major chunks share W panels per XCD)
  const int gx = gridDim.x, gy = gridDim.y;
  const int nb = gx * gy;
  int orig = blockIdx.x + blockIdx.y * gx;
  int id = (orig & 7) * (nb >> 3) + (orig >> 3);
  int tx = id / gy;
  int ty = id - tx * gy;
  const int bm0 = ty * BM;
  const int bn0 = tx * 128;

  // staging map: LDS chunk L = j*512+tid -> row = L/CH, slot = L%CH;
  // source col-chunk = slot ^ (row & (CH-1)); j-invariant since RSTEP%CH==0.
  const int sRow = tid / CH;
  const int sCol = ((tid % CH) ^ (sRow & (CH - 1))) * 8;
  const unsigned short* gA = A + (size_t)(bm0 + sRow) * lda + sCol;
  const unsigned short* gB = B + (size_t)(bn0 + sRow) * ldb + sCol;

  auto STAGE = [&](int buf, int kt) {
    char* base = lds + buf * BUFB;
    const unsigned short* a0 = gA + (size_t)kt * BK;
    const unsigned short* b0 = gB + (size_t)kt * BK;
#pragma unroll
    for (int j = 0; j < AJ; ++j)
      __builtin_amdgcn_global_load_lds(AS1CV(a0 + (size_t)j * RSTEP * lda),
                                       AS3V(base + (j * 512 + tid) * 16), 16, 0, 0);
    char* bb = base + ABYTES;
#pragma unroll
    for (int j = 0; j < BJ; ++j)
      __builtin_amdgcn_global_load_lds(AS1CV(b0 + (size_t)j * RSTEP * ldb),
                                       AS3V(bb + (j * 512 + tid) * 16), 16, 0, 0);
  };

  // read fragments for half h (k-slices 2h, 2h+1) of buffer buf
  auto RHALF = [&](int buf, int h, short8* af, short8* bf) {
    char* base = lds + buf * BUFB;
    char* bb = base + ABYTES;
#pragma unroll
    for (int k2 = 0; k2 < 2; ++k2) {
      const int chunk = (h * 2 + k2) * 2 + lq2;
#pragma unroll
      for (int m = 0; m < MR; ++m) {
        int row = wr * (BM / 2) + m * 32 + l31;
        af[k2 * MR + m] = *(const short8*)(base + row * (2 * BK) +
                                           ((chunk ^ (row & (CH - 1))) * 16));
      }
      {
        int row = wc * 32 + l31;
        bf[k2] = *(const short8*)(bb + row * (2 * BK) +
                                  ((chunk ^ (row & (CH - 1))) * 16));
      }
    }
  };

  f32x16 acc[MR];
#pragma unroll
  for (int m = 0; m < MR; ++m) acc[m] = (f32x16)0.0f;

  auto MHALF = [&](short8* af, short8* bf) {
    __builtin_amdgcn_s_setprio(1);
#pragma unroll
    for (int k2 = 0; k2 < 2; ++k2)
#pragma unroll
      for (int m = 0; m < MR; ++m)
        acc[m] = __builtin_amdgcn_mfma_f32_32x32x16_bf16(af[k2 * MR + m], bf[k2],
                                                         acc[m], 0, 0, 0);
    __builtin_amdgcn_s_setprio(0);
  };

  short8 afA[MR * 2], bfA[2], afB[MR * 2], bfB[2];

  const int nkt = kdim / BK;
  STAGE(0, 0);
  STAGE(1, 1);
  if constexpr (NL == 4) asm volatile("s_waitcnt vmcnt(4)" ::: "memory");
  else                   asm volatile("s_waitcnt vmcnt(3)" ::: "memory");
  __builtin_amdgcn_sched_barrier(0);
  __builtin_amdgcn_s_barrier();
  __builtin_amdgcn_sched_barrier(0);
  RHALF(0, 0, afA, bfA);
  __builtin_amdgcn_sched_barrier(0);

  for (int kt = 0; kt < nkt; ++kt) {
    const int b0 = kt % 3, b1 = (kt + 1) % 3, b2 = (kt + 2) % 3;
    if (kt + 2 < nkt) STAGE(b2, kt + 2);
    RHALF(b0, 1, afB, bfB);              // prefetch half1 under half0's MFMAs
    __builtin_amdgcn_sched_barrier(0);
    MHALF(afA, bfA);
    __builtin_amdgcn_sched_barrier(0);
    if (kt + 1 < nkt) {
      if (kt + 2 < nkt) {
        if constexpr (NL == 4) asm volatile("s_waitcnt vmcnt(8)" ::: "memory");
        else                   asm volatile("s_waitcnt vmcnt(6)" ::: "memory");
        // wait: only stage(kt+2)'s NL may remain -> buf[kt+1] has landed
        if constexpr (NL == 4) asm volatile("s_waitcnt vmcnt(4)" ::: "memory");
        else                   asm volatile("s_waitcnt vmcnt(3)" ::: "memory");
      } else {
        asm volatile("s_waitcnt vmcnt(0)" ::: "memory");
      }
      __builtin_amdgcn_sched_barrier(0);
      __builtin_amdgcn_s_barrier();
      __builtin_amdgcn_sched_barrier(0);
      RHALF(b1, 0, afA, bfA);            // prefetch next tile's half0
      __builtin_amdgcn_sched_barrier(0);
      MHALF(afB, bfB);
      __builtin_amdgcn_sched_barrier(0);
    } else {
      MHALF(afB, bfB);
    }
  }

  // C/D layout (32x32): col = lane&31, row = (r&3) + 8*(r>>2) + 4*(lane>>5)
  if (MODE == 0) {
    int col = bn0 + wc * 32 + l31;
    float bv_ = bias[col];
#pragma unroll
    for (int m = 0; m < MR; ++m) {
      int rbase = bm0 + wr * (BM / 2) + m * 32 + 4 * lq2;
#pragma unroll
      for (int r = 0; r < 16; ++r) {
        int row = rbase + (r & 3) + 8 * (r >> 2);
        float z = acc[m][r] + bv_;
        float p = 1.0f / (1.0f + __expf(-z));
        float u = rng_u(phase, (uint32_t)(row * ldc + col));
        C[(size_t)row * ldc + col] = (u < p) ? (unsigned short)0x3F80 : (unsigned short)0;
      }
    }
  } else {
    float local = 0.0f;
    int col = bn0 + wc * 32 + l31;
    float bv_ = bias[col];
#pragma unroll
    for (int m = 0; m < MR; ++m) {
#pragma unroll
      for (int r = 0; r < 16; ++r) {
        float z = acc[m][r] + bv_;
        local += fmaxf(z, 0.0f) + log1pf(expf(-fabsf(z)));
      }
    }
#pragma unroll
    for (int off = 32; off > 0; off >>= 1) local += __shfl_down(local, off, 64);
    float* red = (float*)lds;
    __syncthreads();
    if (lane == 0) red[wv] = local;
    __syncthreads();
    if (tid == 0)
      fpart[id] = red[0] + red[1] + red[2] + red[3] + red[4] + red[5] + red[6] + red[7];
  }
}

// cost = (Sv + v.bv - Sx - x.bv) / T, double-precision reduce
__global__ void __launch_bounds__(256) finalize(const float* __restrict__ pFx,
                                                const float* __restrict__ pFv,
                                                const float* __restrict__ pXbv,
                                                const float* __restrict__ pVbv,
                                                float* __restrict__ out)
{
  __shared__ double red[256];
  double local = 0.0;
  int t = threadIdx.x;
  for (int i = t; i < 1024; i += 256) {
    if (i < 256)      local -= (double)pFx[i];
    else if (i < 512) local += (double)pFv[i - 256];
    else if (i < 768) local -= (double)pXbv[i - 512];
    else              local += (double)pVbv[i - 768];
  }
  red[t] = local;
  __syncthreads();
  for (int s = 128; s > 0; s >>= 1) {
    if (t < s) red[t] += red[t + s];
    __syncthreads();
  }
  if (t == 0) out[0] = (float)(red[0] / (double)T_ROWS);
}

extern "C" void kernel_launch(void* const* d_in, const int* in_sizes, int n_in,
                              void* d_out, int out_size, void* d_ws, size_t ws_size,
                              hipStream_t stream)
{
  const float* x  = (const float*)d_in[0];
  const float* w  = (const float*)d_in[1];
  const float* bh = (const float*)d_in[2];
  const float* bv = (const float*)d_in[3];

  char* ws = (char*)d_ws;
  unsigned short* Wb  = (unsigned short*)ws;                            // 16 MB
  unsigned short* WTb = (unsigned short*)(ws + (size_t)16777216);       // 16 MB
  unsigned short* Vb  = (unsigned short*)(ws + (size_t)33554432);       //  8 MB
  unsigned short* Hb  = (unsigned short*)(ws + (size_t)41943040);       //  4 MB
  float* pFx  = (float*)(ws + (size_t)46137344);
  float* pFv  = pFx + 256;
  float* pXbv = pFv + 256;
  float* pVbv = pXbv + 256;

  prep_w<<<dim3(NVIS / 64, NHID / 64), 256, 0, stream>>>(w, Wb, WTb);
  xcvt<<<(T_ROWS * NVIS / 4) / 256, 256, 0, stream>>>(x, Vb);

  // F(x): z = x @ W^T + bh  [1024 x 2048]; BM=64 -> grid 16x16 = 256 blocks
  rbm_gemm<1, 64><<<dim3(NHID / 128, T_ROWS / 64), 512, 0, stream>>>(
      Vb, NVIS, Wb, NVIS, bh, nullptr, 0, pFx, NVIS, 0u);
  bvdot<<<256, 256, 0, stream>>>(Vb, bv, pXbv);

  for (int k = 0; k < KGIBBS; ++k) {
    // h ~ Bern(sigmoid(v @ W^T + bh))  [1024 x 2048], 256 blocks
    rbm_gemm<0, 64><<<dim3(NHID / 128, T_ROWS / 64), 512, 0, stream>>>(
        Vb, NVIS, Wb, NVIS, bh, Hb, NHID, nullptr, NVIS, (uint32_t)(2 * k));
    // v ~ Bern(sigmoid(h @ W + bv))    [1024 x 4096], 256 blocks
    rbm_gemm<0, 128><<<dim3(NVIS / 128, T_ROWS / 128), 512, 0, stream>>>(
        Hb, NHID, WTb, NHID, bv, Vb, NVIS, nullptr, NHID, (uint32_t)(2 * k + 1));
  }

  rbm_gemm<1, 64><<<dim3(NHID / 128, T_ROWS / 64), 512, 0, stream>>>(
      Vb, NVIS, Wb, NVIS, bh, nullptr, 0, pFv, NVIS, 0u);
  bvdot<<<256, 256, 0, stream>>>(Vb, bv, pVbv);

  finalize<<<1, 256, 0, stream>>>(pFx, pFv, pXbv, pVbv, (float*)d_out);
}

// Round 7
// 1410.627 us; speedup vs baseline: 1.1784x; 1.1784x over previous
//
#include <hip/hip_runtime.h>
#include <stdint.h>

#define T_ROWS 1024
#define NVIS   4096
#define NHID   2048
#define KGIBBS 25   // K is a static python int (25) in setup_inputs

typedef __attribute__((ext_vector_type(8))) short short8;
typedef __attribute__((ext_vector_type(4))) float f32x4;
typedef __attribute__((ext_vector_type(4))) unsigned short us4;

#define AS1CV(p) ((const __attribute__((address_space(1))) void*)(p))
#define AS3V(p)  ((__attribute__((address_space(3))) void*)(p))

__device__ inline unsigned short f2bf(float f) {
  union { float f; uint32_t u; } c; c.f = f;
  uint32_t u = c.u;
  uint32_t r = (u + 0x7FFFu + ((u >> 16) & 1u)) >> 16;
  return (unsigned short)r;
}

__device__ inline float bf2f(unsigned short s) {
  union { uint32_t u; float f; } c; c.u = ((uint32_t)s) << 16;
  return c.f;
}

// deterministic counter-based uniform in [0,1): murmur3 fmix64 of (phase, idx)
__device__ inline float rng_u(uint32_t phase, uint32_t idx) {
  uint64_t z = (((uint64_t)phase) << 42) | (uint64_t)idx;
  z ^= z >> 33; z *= 0xFF51AFD7ED558CCDULL;
  z ^= z >> 33; z *= 0xC4CEB9FE1A85EC53ULL;
  z ^= z >> 33;
  return (float)(uint32_t)(z >> 40) * (1.0f / 16777216.0f);
}

// ---------------------------------------------------------------------------
// W prep: fp32 -> bf16, plus transposed copy (so both GEMM directions are NT)
// ---------------------------------------------------------------------------
__global__ void __launch_bounds__(256) prep_w(const float* __restrict__ w,
                                              unsigned short* __restrict__ Wb,
                                              unsigned short* __restrict__ WTb)
{
  __shared__ unsigned short tile[64][72];
  const int bi  = blockIdx.x * 64;
  const int bh0 = blockIdx.y * 64;
  const int t   = threadIdx.x;
  const int rr  = t >> 4;
  const int cc  = (t & 15) * 4;
#pragma unroll
  for (int p = 0; p < 4; ++p) {
    int row = p * 16 + rr;
    const float4 v = *(const float4*)&w[(size_t)(bh0 + row) * NVIS + bi + cc];
    unsigned short b0 = f2bf(v.x), b1 = f2bf(v.y), b2 = f2bf(v.z), b3 = f2bf(v.w);
    us4 pk; pk.x = b0; pk.y = b1; pk.z = b2; pk.w = b3;
    *(us4*)&Wb[(size_t)(bh0 + row) * NVIS + bi + cc] = pk;
    tile[cc + 0][row] = b0; tile[cc + 1][row] = b1;
    tile[cc + 2][row] = b2; tile[cc + 3][row] = b3;
  }
  __syncthreads();
#pragma unroll
  for (int p = 0; p < 4; ++p) {
    int row = p * 16 + rr;
    us4 pk;
    pk.x = tile[row][cc + 0]; pk.y = tile[row][cc + 1];
    pk.z = tile[row][cc + 2]; pk.w = tile[row][cc + 3];
    *(us4*)&WTb[(size_t)(bi + row) * NHID + bh0 + cc] = pk;
  }
}

__global__ void __launch_bounds__(256) xcvt(const float* __restrict__ x,
                                            unsigned short* __restrict__ Vb)
{
  int i = blockIdx.x * 256 + threadIdx.x;
  const float4 v = ((const float4*)x)[i];
  us4 pk; pk.x = f2bf(v.x); pk.y = f2bf(v.y); pk.z = f2bf(v.z); pk.w = f2bf(v.w);
  ((us4*)Vb)[i] = pk;
}

__global__ void __launch_bounds__(256) bvdot(const unsigned short* __restrict__ V,
                                             const float* __restrict__ bv,
                                             float* __restrict__ part)
{
  float local = 0.f;
  for (int v = blockIdx.x * 256 + threadIdx.x; v < T_ROWS * NVIS / 4; v += 256 * 256) {
    int col4 = (v & (NVIS / 4 - 1)) * 4;
    us4 a = ((const us4*)V)[v];
    float4 b = *(const float4*)&bv[col4];
    local += bf2f(a.x) * b.x + bf2f(a.y) * b.y + bf2f(a.z) * b.z + bf2f(a.w) * b.w;
  }
#pragma unroll
  for (int off = 32; off > 0; off >>= 1) local += __shfl_down(local, off, 64);
  __shared__ float red[4];
  if ((threadIdx.x & 63) == 0) red[threadIdx.x >> 6] = local;
  __syncthreads();
  if (threadIdx.x == 0) part[blockIdx.x] = red[0] + red[1] + red[2] + red[3];
}

// ---------------------------------------------------------------------------
// GEMM: C[M,N] = A[M,K] * B^T, B stored [N][K]. BN=128 fixed; BM, BK template.
// 512 threads = 8 waves (2 M x 4 N). 16x16x32 bf16 MFMA, wave tile (BM/2)x32.
// 3-buffer LDS pipeline, stage-ahead-2 issued AFTER the barrier (race-free:
// all waves are past the last read of the target buffer), counted vmcnt
// (never 0 mid-loop).
// MODE 0: C = bernoulli(sigmoid(z + bias)) bf16 {0,1}
// MODE 1: fpart[block] = sum softplus(z + bias)
// ---------------------------------------------------------------------------
template <int MODE, int BM, int BK>
__global__ void __launch_bounds__(512, 2)
rbm_gemm(const unsigned short* __restrict__ A, int lda,
         const unsigned short* __restrict__ B, int ldb,
         const float* __restrict__ bias,
         unsigned short* __restrict__ C, int ldc,
         float* __restrict__ fpart,
         int kdim, uint32_t phase)
{
  constexpr int MR = BM / 32;            // 16-row frags per wave (M)
  constexpr int CH = BK / 8;             // 16B chunks per LDS row
  constexpr int ABYTES = BM * BK * 2;
  constexpr int BBYTES = 128 * BK * 2;
  constexpr int BUFB = ABYTES + BBYTES;
  constexpr int AJ = ABYTES / 8192;      // A loads per thread per stage
  constexpr int BJ = BBYTES / 8192;      // B loads per thread per stage
  constexpr int NL = AJ + BJ;            // loads in flight per stage
  constexpr int RSTEP = 512 / CH;        // rows per j step
  __shared__ __align__(16) char lds[3 * BUFB];

  const int tid  = threadIdx.x;
  const int lane = tid & 63;
  const int wv   = tid >> 6;
  const int wr   = wv >> 2;              // 0..1  (M)
  const int wc   = wv & 3;               // 0..3  (N)
  const int lr   = lane & 15;
  const int lq   = lane >> 4;

  // XCD-chunked tile swizzle (col-major chunks share W panels per XCD)
  const int gx = gridDim.x, gy = gridDim.y;
  const int nb = gx * gy;
  int orig = blockIdx.x + blockIdx.y * gx;
  int id = (orig & 7) * (nb >> 3) + (orig >> 3);
  int tx = id / gy;
  int ty = id - tx * gy;
  const int bm0 = ty * BM;
  const int bn0 = tx * 128;

  // staging map: LDS chunk L = j*512+tid -> row = L/CH, slot = L%CH;
  // source col-chunk = slot ^ (row & (CH-1)); j-invariant since RSTEP%CH==0.
  const int sRow = tid / CH;
  const int sCol = ((tid % CH) ^ (sRow & (CH - 1))) * 8;
  const unsigned short* gA = A + (size_t)(bm0 + sRow) * lda + sCol;
  const unsigned short* gB = B + (size_t)(bn0 + sRow) * ldb + sCol;

  auto STAGE = [&](int buf, int kt) {
    char* base = lds + buf * BUFB;
    const unsigned short* a0 = gA + (size_t)kt * BK;
    const unsigned short* b0 = gB + (size_t)kt * BK;
#pragma unroll
    for (int j = 0; j < AJ; ++j)
      __builtin_amdgcn_global_load_lds(AS1CV(a0 + (size_t)j * RSTEP * lda),
                                       AS3V(base + (j * 512 + tid) * 16), 16, 0, 0);
    char* bb = base + ABYTES;
#pragma unroll
    for (int j = 0; j < BJ; ++j)
      __builtin_amdgcn_global_load_lds(AS1CV(b0 + (size_t)j * RSTEP * ldb),
                                       AS3V(bb + (j * 512 + tid) * 16), 16, 0, 0);
  };

  f32x4 acc[MR][2];
#pragma unroll
  for (int m = 0; m < MR; ++m)
#pragma unroll
    for (int n = 0; n < 2; ++n) acc[m][n] = (f32x4)0.0f;

  const int nkt = kdim / BK;
  STAGE(0, 0);
  STAGE(1, 1);

  for (int kt = 0; kt < nkt; ++kt) {
    if (kt + 1 < nkt) {
      // current tile landed; at most the next stage's NL loads stay in flight
      if constexpr (NL == 6)      asm volatile("s_waitcnt vmcnt(6)" ::: "memory");
      else if constexpr (NL == 4) asm volatile("s_waitcnt vmcnt(4)" ::: "memory");
      else                        asm volatile("s_waitcnt vmcnt(8)" ::: "memory");
    } else {
      asm volatile("s_waitcnt vmcnt(0)" ::: "memory");
    }
    __builtin_amdgcn_sched_barrier(0);
    __builtin_amdgcn_s_barrier();
    __builtin_amdgcn_sched_barrier(0);

    // stage-ahead-2, issued after the barrier: every wave is past its last
    // read of buffer (kt+2)%3 (those reads happened at iter kt-1).
    if (kt + 2 < nkt) STAGE((kt + 2) % 3, kt + 2);

    char* base = lds + (kt % 3) * BUFB;
    char* bb = base + ABYTES;
#pragma unroll
    for (int ks = 0; ks < BK / 32; ++ks) {
      short8 af[MR], bfr[2];
#pragma unroll
      for (int m = 0; m < MR; ++m) {
        int row = wr * (BM / 2) + m * 16 + lr;
        af[m] = *(const short8*)(base + row * (2 * BK) +
                                 (((ks * 4 + lq) ^ (row & (CH - 1))) * 16));
      }
#pragma unroll
      for (int n = 0; n < 2; ++n) {
        int row = wc * 32 + n * 16 + lr;
        bfr[n] = *(const short8*)(bb + row * (2 * BK) +
                                  (((ks * 4 + lq) ^ (row & (CH - 1))) * 16));
      }
#pragma unroll
      for (int m = 0; m < MR; ++m)
#pragma unroll
        for (int n = 0; n < 2; ++n)
          acc[m][n] = __builtin_amdgcn_mfma_f32_16x16x32_bf16(af[m], bfr[n], acc[m][n], 0, 0, 0);
    }
  }

  if (MODE == 0) {
#pragma unroll
    for (int n = 0; n < 2; ++n) {
      int col = bn0 + wc * 32 + n * 16 + lr;
      float bv_ = bias[col];
#pragma unroll
      for (int m = 0; m < MR; ++m) {
        int row0 = bm0 + wr * (BM / 2) + m * 16 + lq * 4;
#pragma unroll
        for (int j = 0; j < 4; ++j) {
          int row = row0 + j;
          float z = acc[m][n][j] + bv_;
          float p = 1.0f / (1.0f + __expf(-z));
          float u = rng_u(phase, (uint32_t)(row * ldc + col));
          C[(size_t)row * ldc + col] = (u < p) ? (unsigned short)0x3F80 : (unsigned short)0;
        }
      }
    }
  } else {
    float local = 0.0f;
#pragma unroll
    for (int n = 0; n < 2; ++n) {
      int col = bn0 + wc * 32 + n * 16 + lr;
      float bv_ = bias[col];
#pragma unroll
      for (int m = 0; m < MR; ++m) {
#pragma unroll
        for (int j = 0; j < 4; ++j) {
          float z = acc[m][n][j] + bv_;
          local += fmaxf(z, 0.0f) + log1pf(expf(-fabsf(z)));
        }
      }
    }
#pragma unroll
    for (int off = 32; off > 0; off >>= 1) local += __shfl_down(local, off, 64);
    float* red = (float*)lds;
    __syncthreads();
    if (lane == 0) red[wv] = local;
    __syncthreads();
    if (tid == 0)
      fpart[id] = red[0] + red[1] + red[2] + red[3] + red[4] + red[5] + red[6] + red[7];
  }
}

// cost = (Sv + v.bv - Sx - x.bv) / T, double-precision reduce
__global__ void __launch_bounds__(256) finalize(const float* __restrict__ pFx,
                                                const float* __restrict__ pFv,
                                                const float* __restrict__ pXbv,
                                                const float* __restrict__ pVbv,
                                                float* __restrict__ out)
{
  __shared__ double red[256];
  double local = 0.0;
  int t = threadIdx.x;
  for (int i = t; i < 1024; i += 256) {
    if (i < 256)      local -= (double)pFx[i];
    else if (i < 512) local += (double)pFv[i - 256];
    else if (i < 768) local -= (double)pXbv[i - 512];
    else              local += (double)pVbv[i - 768];
  }
  red[t] = local;
  __syncthreads();
  for (int s = 128; s > 0; s >>= 1) {
    if (t < s) red[t] += red[t + s];
    __syncthreads();
  }
  if (t == 0) out[0] = (float)(red[0] / (double)T_ROWS);
}

extern "C" void kernel_launch(void* const* d_in, const int* in_sizes, int n_in,
                              void* d_out, int out_size, void* d_ws, size_t ws_size,
                              hipStream_t stream)
{
  const float* x  = (const float*)d_in[0];
  const float* w  = (const float*)d_in[1];
  const float* bh = (const float*)d_in[2];
  const float* bv = (const float*)d_in[3];

  char* ws = (char*)d_ws;
  unsigned short* Wb  = (unsigned short*)ws;                            // 16 MB
  unsigned short* WTb = (unsigned short*)(ws + (size_t)16777216);       // 16 MB
  unsigned short* Vb  = (unsigned short*)(ws + (size_t)33554432);       //  8 MB
  unsigned short* Hb  = (unsigned short*)(ws + (size_t)41943040);       //  4 MB
  float* pFx  = (float*)(ws + (size_t)46137344);
  float* pFv  = pFx + 256;
  float* pXbv = pFv + 256;
  float* pVbv = pXbv + 256;

  prep_w<<<dim3(NVIS / 64, NHID / 64), 256, 0, stream>>>(w, Wb, WTb);
  xcvt<<<(T_ROWS * NVIS / 4) / 256, 256, 0, stream>>>(x, Vb);

  // F(x): z = x @ W^T + bh  [1024 x 2048]; BM=64,BK=128 -> 16x16 = 256 blocks
  rbm_gemm<1, 64, 128><<<dim3(NHID / 128, T_ROWS / 64), 512, 0, stream>>>(
      Vb, NVIS, Wb, NVIS, bh, nullptr, 0, pFx, NVIS, 0u);
  bvdot<<<256, 256, 0, stream>>>(Vb, bv, pXbv);

  for (int k = 0; k < KGIBBS; ++k) {
    // h ~ Bern(sigmoid(v @ W^T + bh))  [1024 x 2048], 256 blocks
    rbm_gemm<0, 64, 128><<<dim3(NHID / 128, T_ROWS / 64), 512, 0, stream>>>(
        Vb, NVIS, Wb, NVIS, bh, Hb, NHID, nullptr, NVIS, (uint32_t)(2 * k));
    // v ~ Bern(sigmoid(h @ W + bv))    [1024 x 4096], 256 blocks
    rbm_gemm<0, 128, 64><<<dim3(NVIS / 128, T_ROWS / 128), 512, 0, stream>>>(
        Hb, NHID, WTb, NHID, bv, Vb, NVIS, nullptr, NHID, (uint32_t)(2 * k + 1));
  }

  rbm_gemm<1, 64, 128><<<dim3(NHID / 128, T_ROWS / 64), 512, 0, stream>>>(
      Vb, NVIS, Wb, NVIS, bh, nullptr, 0, pFv, NVIS, 0u);
  bvdot<<<256, 256, 0, stream>>>(Vb, bv, pVbv);

  finalize<<<1, 256, 0, stream>>>(pFx, pFv, pXbv, pVbv, (float*)d_out);
}

// Round 8
// 1216.649 us; speedup vs baseline: 1.3663x; 1.1594x over previous
//
#include <hip/hip_runtime.h>
#include <hip/hip_fp8.h>
#include <stdint.h>

#define T_ROWS 1024
#define NVIS   4096
#define NHID   2048
#define KGIBBS 25   // K is a static python int (25) in setup_inputs

typedef __attribute__((ext_vector_type(8))) short short8;
typedef __attribute__((ext_vector_type(4))) float f32x4;
typedef __attribute__((ext_vector_type(4))) unsigned short us4;

#define AS1CV(p) ((const __attribute__((address_space(1))) void*)(p))
#define AS3V(p)  ((__attribute__((address_space(3))) void*)(p))

__device__ inline unsigned short f2bf(float f) {
  union { float f; uint32_t u; } c; c.f = f;
  uint32_t u = c.u;
  uint32_t r = (u + 0x7FFFu + ((u >> 16) & 1u)) >> 16;
  return (unsigned short)r;
}

__device__ inline float bf2f(unsigned short s) {
  union { uint32_t u; float f; } c; c.u = ((uint32_t)s) << 16;
  return c.f;
}

__device__ inline unsigned char f2e4m3(float f) {
  __hip_fp8_e4m3 q(f);               // OCP e4m3fn on gfx950
  return (unsigned char)q.__x;
}

// deterministic counter-based uniform in [0,1): murmur3 fmix64 of (phase, idx)
__device__ inline float rng_u(uint32_t phase, uint32_t idx) {
  uint64_t z = (((uint64_t)phase) << 42) | (uint64_t)idx;
  z ^= z >> 33; z *= 0xFF51AFD7ED558CCDULL;
  z ^= z >> 33; z *= 0xC4CEB9FE1A85EC53ULL;
  z ^= z >> 33;
  return (float)(uint32_t)(z >> 40) * (1.0f / 16777216.0f);
}

// ---------------------------------------------------------------------------
// W prep: fp32 -> Wb (bf16, [NH][NV]) for the F-energy GEMMs, plus
// W8 = e4m3(w*64) [NH][NV] and WT8 = e4m3(w*64) [NV][NH] for the fp8 chain.
// ---------------------------------------------------------------------------
__global__ void __launch_bounds__(256) prep_w(const float* __restrict__ w,
                                              unsigned short* __restrict__ Wb,
                                              unsigned char* __restrict__ W8,
                                              unsigned char* __restrict__ WT8)
{
  __shared__ unsigned char t8[64][68];
  const int bi  = blockIdx.x * 64;   // NV offset
  const int bh0 = blockIdx.y * 64;   // NH offset
  const int t   = threadIdx.x;
  const int rr  = t >> 4;            // 0..15
  const int cc  = (t & 15) * 4;      // 0,4,..,60
#pragma unroll
  for (int p = 0; p < 4; ++p) {
    int row = p * 16 + rr;
    const float4 v = *(const float4*)&w[(size_t)(bh0 + row) * NVIS + bi + cc];
    us4 pk; pk.x = f2bf(v.x); pk.y = f2bf(v.y); pk.z = f2bf(v.z); pk.w = f2bf(v.w);
    *(us4*)&Wb[(size_t)(bh0 + row) * NVIS + bi + cc] = pk;
    unsigned char b0 = f2e4m3(v.x * 64.f), b1 = f2e4m3(v.y * 64.f);
    unsigned char b2 = f2e4m3(v.z * 64.f), b3 = f2e4m3(v.w * 64.f);
    uint32_t w8pk = (uint32_t)b0 | ((uint32_t)b1 << 8) |
                    ((uint32_t)b2 << 16) | ((uint32_t)b3 << 24);
    *(uint32_t*)&W8[(size_t)(bh0 + row) * NVIS + bi + cc] = w8pk;
    t8[cc + 0][row] = b0; t8[cc + 1][row] = b1;
    t8[cc + 2][row] = b2; t8[cc + 3][row] = b3;
  }
  __syncthreads();
#pragma unroll
  for (int p = 0; p < 4; ++p) {
    int irow = p * 16 + rr;          // NV-local
    uint32_t o = (uint32_t)t8[irow][cc + 0] | ((uint32_t)t8[irow][cc + 1] << 8) |
                 ((uint32_t)t8[irow][cc + 2] << 16) | ((uint32_t)t8[irow][cc + 3] << 24);
    *(uint32_t*)&WT8[(size_t)(bi + irow) * NHID + bh0 + cc] = o;
  }
}

// x (fp32 0/1) -> bf16 Vb and fp8 V8
__global__ void __launch_bounds__(256) xcvt(const float* __restrict__ x,
                                            unsigned short* __restrict__ Vb,
                                            unsigned char* __restrict__ V8)
{
  int i = blockIdx.x * 256 + threadIdx.x;
  const float4 v = ((const float4*)x)[i];
  us4 pk; pk.x = f2bf(v.x); pk.y = f2bf(v.y); pk.z = f2bf(v.z); pk.w = f2bf(v.w);
  ((us4*)Vb)[i] = pk;
  uint32_t p8 = (uint32_t)f2e4m3(v.x) | ((uint32_t)f2e4m3(v.y) << 8) |
                ((uint32_t)f2e4m3(v.z) << 16) | ((uint32_t)f2e4m3(v.w) << 24);
  ((uint32_t*)V8)[i] = p8;
}

__global__ void __launch_bounds__(256) bvdot(const unsigned short* __restrict__ V,
                                             const float* __restrict__ bv,
                                             float* __restrict__ part)
{
  float local = 0.f;
  for (int v = blockIdx.x * 256 + threadIdx.x; v < T_ROWS * NVIS / 4; v += 256 * 256) {
    int col4 = (v & (NVIS / 4 - 1)) * 4;
    us4 a = ((const us4*)V)[v];
    float4 b = *(const float4*)&bv[col4];
    local += bf2f(a.x) * b.x + bf2f(a.y) * b.y + bf2f(a.z) * b.z + bf2f(a.w) * b.w;
  }
#pragma unroll
  for (int off = 32; off > 0; off >>= 1) local += __shfl_down(local, off, 64);
  __shared__ float red[4];
  if ((threadIdx.x & 63) == 0) red[threadIdx.x >> 6] = local;
  __syncthreads();
  if (threadIdx.x == 0) part[blockIdx.x] = red[0] + red[1] + red[2] + red[3];
}

// ---------------------------------------------------------------------------
// bf16 GEMM (R3 schedule, unchanged): used only for the two F-energy passes.
// C[M,N] = A[M,K]*B^T, B stored [N][K]. 512 thr = 8 waves (2Mx4N), 16x16x32.
// MODE 1: fpart[block] = sum softplus(z + bias)
// ---------------------------------------------------------------------------
template <int MODE, int BM, int BK>
__global__ void __launch_bounds__(512, 2)
rbm_gemm(const unsigned short* __restrict__ A, int lda,
         const unsigned short* __restrict__ B, int ldb,
         const float* __restrict__ bias,
         unsigned short* __restrict__ C, int ldc,
         float* __restrict__ fpart,
         int kdim, uint32_t phase)
{
  constexpr int MR = BM / 32;
  constexpr int CH = BK / 8;
  constexpr int ABYTES = BM * BK * 2;
  constexpr int BBYTES = 128 * BK * 2;
  constexpr int BUFB = ABYTES + BBYTES;
  constexpr int AJ = ABYTES / 8192;
  constexpr int BJ = BBYTES / 8192;
  constexpr int NL = AJ + BJ;
  constexpr int RSTEP = 512 / CH;
  __shared__ __align__(16) char lds[3 * BUFB];

  const int tid  = threadIdx.x;
  const int lane = tid & 63;
  const int wv   = tid >> 6;
  const int wr   = wv >> 2;
  const int wc   = wv & 3;
  const int lr   = lane & 15;
  const int lq   = lane >> 4;

  const int gx = gridDim.x, gy = gridDim.y;
  const int nb = gx * gy;
  int orig = blockIdx.x + blockIdx.y * gx;
  int id = (orig & 7) * (nb >> 3) + (orig >> 3);
  int tx = id / gy;
  int ty = id - tx * gy;
  const int bm0 = ty * BM;
  const int bn0 = tx * 128;

  const int sRow = tid / CH;
  const int sCol = ((tid % CH) ^ (sRow & (CH - 1))) * 8;
  const unsigned short* gA = A + (size_t)(bm0 + sRow) * lda + sCol;
  const unsigned short* gB = B + (size_t)(bn0 + sRow) * ldb + sCol;

  auto STAGE = [&](int buf, int kt) {
    char* base = lds + buf * BUFB;
    const unsigned short* a0 = gA + (size_t)kt * BK;
    const unsigned short* b0 = gB + (size_t)kt * BK;
#pragma unroll
    for (int j = 0; j < AJ; ++j)
      __builtin_amdgcn_global_load_lds(AS1CV(a0 + (size_t)j * RSTEP * lda),
                                       AS3V(base + (j * 512 + tid) * 16), 16, 0, 0);
    char* bb = base + ABYTES;
#pragma unroll
    for (int j = 0; j < BJ; ++j)
      __builtin_amdgcn_global_load_lds(AS1CV(b0 + (size_t)j * RSTEP * ldb),
                                       AS3V(bb + (j * 512 + tid) * 16), 16, 0, 0);
  };

  f32x4 acc[MR][2];
#pragma unroll
  for (int m = 0; m < MR; ++m)
#pragma unroll
    for (int n = 0; n < 2; ++n) acc[m][n] = (f32x4)0.0f;

  const int nkt = kdim / BK;
  STAGE(0, 0);

  int cur = 0;
  for (int kt = 0; kt < nkt; ++kt) {
    int nxt = (cur == 2) ? 0 : cur + 1;
    if (kt + 1 < nkt) {
      STAGE(nxt, kt + 1);
      if constexpr (NL == 6)      asm volatile("s_waitcnt vmcnt(6)" ::: "memory");
      else if constexpr (NL == 4) asm volatile("s_waitcnt vmcnt(4)" ::: "memory");
      else                        asm volatile("s_waitcnt vmcnt(8)" ::: "memory");
    } else {
      asm volatile("s_waitcnt vmcnt(0)" ::: "memory");
    }
    __builtin_amdgcn_sched_barrier(0);
    __builtin_amdgcn_s_barrier();
    __builtin_amdgcn_sched_barrier(0);

    char* base = lds + cur * BUFB;
    char* bb = base + ABYTES;
#pragma unroll
    for (int ks = 0; ks < BK / 32; ++ks) {
      short8 af[MR], bfr[2];
#pragma unroll
      for (int m = 0; m < MR; ++m) {
        int row = wr * (BM / 2) + m * 16 + lr;
        af[m] = *(const short8*)(base + row * (2 * BK) +
                                 (((ks * 4 + lq) ^ (row & (CH - 1))) * 16));
      }
#pragma unroll
      for (int n = 0; n < 2; ++n) {
        int row = wc * 32 + n * 16 + lr;
        bfr[n] = *(const short8*)(bb + row * (2 * BK) +
                                  (((ks * 4 + lq) ^ (row & (CH - 1))) * 16));
      }
#pragma unroll
      for (int m = 0; m < MR; ++m)
#pragma unroll
        for (int n = 0; n < 2; ++n)
          acc[m][n] = __builtin_amdgcn_mfma_f32_16x16x32_bf16(af[m], bfr[n], acc[m][n], 0, 0, 0);
    }
    cur = nxt;
  }

  if (MODE == 0) {
#pragma unroll
    for (int n = 0; n < 2; ++n) {
      int col = bn0 + wc * 32 + n * 16 + lr;
      float bv_ = bias[col];
#pragma unroll
      for (int m = 0; m < MR; ++m) {
        int row0 = bm0 + wr * (BM / 2) + m * 16 + lq * 4;
#pragma unroll
        for (int j = 0; j < 4; ++j) {
          int row = row0 + j;
          float z = acc[m][n][j] + bv_;
          float p = 1.0f / (1.0f + __expf(-z));
          float u = rng_u(phase, (uint32_t)(row * ldc + col));
          C[(size_t)row * ldc + col] = (u < p) ? (unsigned short)0x3F80 : (unsigned short)0;
        }
      }
    }
  } else {
    float local = 0.0f;
#pragma unroll
    for (int n = 0; n < 2; ++n) {
      int col = bn0 + wc * 32 + n * 16 + lr;
      float bv_ = bias[col];
#pragma unroll
      for (int m = 0; m < MR; ++m) {
#pragma unroll
        for (int j = 0; j < 4; ++j) {
          float z = acc[m][n][j] + bv_;
          local += fmaxf(z, 0.0f) + log1pf(expf(-fabsf(z)));
        }
      }
    }
#pragma unroll
    for (int off = 32; off > 0; off >>= 1) local += __shfl_down(local, off, 64);
    float* red = (float*)lds;
    __syncthreads();
    if (lane == 0) red[wv] = local;
    __syncthreads();
    if (tid == 0)
      fpart[id] = red[0] + red[1] + red[2] + red[3] + red[4] + red[5] + red[6] + red[7];
  }
}

// ---------------------------------------------------------------------------
// fp8 chain GEMM: C = bernoulli(sigmoid(acc/64 + bias)). A [M][K] e4m3 {0,1},
// B [N][K] e4m3 (w*64). BK=128 (128 B/row, CH=8). 512 thr = 8 waves (2Mx4N),
// 16x16x32 fp8 MFMA (frag = 8 B = long). R3 schedule: 3-buffer, stage-ahead-1
// before counted vmcnt. Writes fp8 sample; optionally bf16 copy (last iter).
// ---------------------------------------------------------------------------
template <int BM>
__global__ void __launch_bounds__(512, 2)
rbm_gemm8(const unsigned char* __restrict__ A, int lda,
          const unsigned char* __restrict__ B, int ldb,
          const float* __restrict__ bias,
          unsigned char* __restrict__ C8,
          unsigned short* __restrict__ Cb, int ldc,
          int kdim, uint32_t phase, int wbf)
{
  constexpr int BK = 128;
  constexpr int MR = BM / 32;
  constexpr int ABYTES = BM * BK;       // 1 B/elem
  constexpr int BBYTES = 128 * BK;
  constexpr int BUFB = ABYTES + BBYTES;
  constexpr int AJ = ABYTES / 8192;     // 1 or 2
  constexpr int BJ = BBYTES / 8192;     // 2
  constexpr int NL = AJ + BJ;           // 3 or 4
  __shared__ __align__(16) char lds[3 * BUFB];

  const int tid  = threadIdx.x;
  const int lane = tid & 63;
  const int wv   = tid >> 6;
  const int wr   = wv >> 2;             // 0..1 (M)
  const int wc   = wv & 3;              // 0..3 (N)
  const int lr   = lane & 15;
  const int lq   = lane >> 4;           // 0..3

  const int gx = gridDim.x, gy = gridDim.y;
  const int nb = gx * gy;
  int orig = blockIdx.x + blockIdx.y * gx;
  int id = (orig & 7) * (nb >> 3) + (orig >> 3);
  int tx = id / gy;
  int ty = id - tx * gy;
  const int bm0 = ty * BM;
  const int bn0 = tx * 128;

  // staging: chunk L = j*512+tid -> row=L/8, slot=L%8; src chunk = slot^(row&7)
  const int sRow = tid >> 3;            // 0..63
  const int sCol = (((tid & 7) ^ (sRow & 7)) * 16);
  const unsigned char* gA = A + (size_t)(bm0 + sRow) * lda + sCol;
  const unsigned char* gB = B + (size_t)(bn0 + sRow) * ldb + sCol;

  auto STAGE = [&](int buf, int kt) {
    char* base = lds + buf * BUFB;
    const unsigned char* a0 = gA + (size_t)kt * BK;
    const unsigned char* b0 = gB + (size_t)kt * BK;
#pragma unroll
    for (int j = 0; j < AJ; ++j)
      __builtin_amdgcn_global_load_lds(AS1CV(a0 + (size_t)j * 64 * lda),
                                       AS3V(base + (j * 512 + tid) * 16), 16, 0, 0);
    char* bb = base + ABYTES;
#pragma unroll
    for (int j = 0; j < BJ; ++j)
      __builtin_amdgcn_global_load_lds(AS1CV(b0 + (size_t)j * 64 * ldb),
                                       AS3V(bb + (j * 512 + tid) * 16), 16, 0, 0);
  };

  f32x4 acc[MR][2];
#pragma unroll
  for (int m = 0; m < MR; ++m)
#pragma unroll
    for (int n = 0; n < 2; ++n) acc[m][n] = (f32x4)0.0f;

  const int nkt = kdim / BK;
  STAGE(0, 0);

  int cur = 0;
  for (int kt = 0; kt < nkt; ++kt) {
    int nxt = (cur == 2) ? 0 : cur + 1;
    if (kt + 1 < nkt) {
      STAGE(nxt, kt + 1);
      if constexpr (NL == 3) asm volatile("s_waitcnt vmcnt(3)" ::: "memory");
      else                   asm volatile("s_waitcnt vmcnt(4)" ::: "memory");
    } else {
      asm volatile("s_waitcnt vmcnt(0)" ::: "memory");
    }
    __builtin_amdgcn_sched_barrier(0);
    __builtin_amdgcn_s_barrier();
    __builtin_amdgcn_sched_barrier(0);

    char* base = lds + cur * BUFB;
    char* bb = base + ABYTES;
#pragma unroll
    for (int ks = 0; ks < 4; ++ks) {          // K-slices of 32
      long af[MR], bfr[2];
      const int cb  = ks * 2 + (lq >> 1);     // 16B chunk index
      const int sub = (lq & 1) * 8;           // 8B within chunk
#pragma unroll
      for (int m = 0; m < MR; ++m) {
        int row = wr * (BM / 2) + m * 16 + lr;
        af[m] = *(const long*)(base + row * BK + ((cb ^ (row & 7)) * 16) + sub);
      }
#pragma unroll
      for (int n = 0; n < 2; ++n) {
        int row = wc * 32 + n * 16 + lr;
        bfr[n] = *(const long*)(bb + row * BK + ((cb ^ (row & 7)) * 16) + sub);
      }
#pragma unroll
      for (int m = 0; m < MR; ++m)
#pragma unroll
        for (int n = 0; n < 2; ++n)
          acc[m][n] = __builtin_amdgcn_mfma_f32_16x16x32_fp8_fp8(af[m], bfr[n], acc[m][n], 0, 0, 0);
    }
    cur = nxt;
  }

  // epilogue: z = acc/64 + bias; sample; write fp8 (+ optional bf16)
#pragma unroll
  for (int n = 0; n < 2; ++n) {
    int col = bn0 + wc * 32 + n * 16 + lr;
    float bv_ = bias[col];
#pragma unroll
    for (int m = 0; m < MR; ++m) {
      int row0 = bm0 + wr * (BM / 2) + m * 16 + lq * 4;
#pragma unroll
      for (int j = 0; j < 4; ++j) {
        int row = row0 + j;
        float z = acc[m][n][j] * 0.015625f + bv_;
        float p = 1.0f / (1.0f + __expf(-z));
        float u = rng_u(phase, (uint32_t)(row * ldc + col));
        unsigned char s = (u < p) ? (unsigned char)0x38 : (unsigned char)0; // e4m3 1.0
        C8[(size_t)row * ldc + col] = s;
        if (wbf)
          Cb[(size_t)row * ldc + col] = (u < p) ? (unsigned short)0x3F80 : (unsigned short)0;
      }
    }
  }
}

// cost = (Sv + v.bv - Sx - x.bv) / T, double-precision reduce
__global__ void __launch_bounds__(256) finalize(const float* __restrict__ pFx,
                                                const float* __restrict__ pFv,
                                                const float* __restrict__ pXbv,
                                                const float* __restrict__ pVbv,
                                                float* __restrict__ out)
{
  __shared__ double red[256];
  double local = 0.0;
  int t = threadIdx.x;
  for (int i = t; i < 1024; i += 256) {
    if (i < 256)      local -= (double)pFx[i];
    else if (i < 512) local += (double)pFv[i - 256];
    else if (i < 768) local -= (double)pXbv[i - 512];
    else              local += (double)pVbv[i - 768];
  }
  red[t] = local;
  __syncthreads();
  for (int s = 128; s > 0; s >>= 1) {
    if (t < s) red[t] += red[t + s];
    __syncthreads();
  }
  if (t == 0) out[0] = (float)(red[0] / (double)T_ROWS);
}

extern "C" void kernel_launch(void* const* d_in, const int* in_sizes, int n_in,
                              void* d_out, int out_size, void* d_ws, size_t ws_size,
                              hipStream_t stream)
{
  const float* x  = (const float*)d_in[0];
  const float* w  = (const float*)d_in[1];
  const float* bh = (const float*)d_in[2];
  const float* bv = (const float*)d_in[3];

  char* ws = (char*)d_ws;
  unsigned short* Wb  = (unsigned short*)ws;                            // 16 MB
  unsigned char*  W8  = (unsigned char*)(ws + (size_t)16777216);        //  8 MB
  unsigned char*  WT8 = (unsigned char*)(ws + (size_t)25165824);        //  8 MB
  unsigned short* Vb  = (unsigned short*)(ws + (size_t)33554432);       //  8 MB
  unsigned char*  V8  = (unsigned char*)(ws + (size_t)41943040);        //  4 MB
  unsigned char*  H8  = (unsigned char*)(ws + (size_t)46137344);        //  2 MB
  float* pFx  = (float*)(ws + (size_t)48234496);
  float* pFv  = pFx + 256;
  float* pXbv = pFv + 256;
  float* pVbv = pXbv + 256;

  prep_w<<<dim3(NVIS / 64, NHID / 64), 256, 0, stream>>>(w, Wb, W8, WT8);
  xcvt<<<(T_ROWS * NVIS / 4) / 256, 256, 0, stream>>>(x, Vb, V8);

  // F(x): z = x @ W^T + bh  [1024 x 2048] (bf16, exact path)
  rbm_gemm<1, 64, 128><<<dim3(NHID / 128, T_ROWS / 64), 512, 0, stream>>>(
      Vb, NVIS, Wb, NVIS, bh, nullptr, 0, pFx, NVIS, 0u);
  bvdot<<<256, 256, 0, stream>>>(Vb, bv, pXbv);

  for (int k = 0; k < KGIBBS; ++k) {
    // h ~ Bern(sigmoid(v @ W^T + bh))  [1024 x 2048], fp8, 256 blocks
    rbm_gemm8<64><<<dim3(NHID / 128, T_ROWS / 64), 512, 0, stream>>>(
        V8, NVIS, W8, NVIS, bh, H8, nullptr, NHID, NVIS, (uint32_t)(2 * k), 0);
    // v ~ Bern(sigmoid(h @ W + bv))    [1024 x 4096], fp8, 256 blocks
    rbm_gemm8<128><<<dim3(NVIS / 128, T_ROWS / 128), 512, 0, stream>>>(
        H8, NHID, WT8, NHID, bv, V8, Vb, NVIS, NHID, (uint32_t)(2 * k + 1),
        (k == KGIBBS - 1) ? 1 : 0);
  }

  // F(v_o) (bf16, exact path; Vb written by the last v-GEMM)
  rbm_gemm<1, 64, 128><<<dim3(NHID / 128, T_ROWS / 64), 512, 0, stream>>>(
      Vb, NVIS, Wb, NVIS, bh, nullptr, 0, pFv, NVIS, 0u);
  bvdot<<<256, 256, 0, stream>>>(Vb, bv, pVbv);

  finalize<<<1, 256, 0, stream>>>(pFx, pFv, pXbv, pVbv, (float*)d_out);
}

// Round 9
// 1212.061 us; speedup vs baseline: 1.3715x; 1.0038x over previous
//
#include <hip/hip_runtime.h>
#include <hip/hip_fp8.h>
#include <stdint.h>

#define T_ROWS 1024
#define NVIS   4096
#define NHID   2048
#define KGIBBS 25   // K is a static python int (25) in setup_inputs

typedef __attribute__((ext_vector_type(8))) short short8;
typedef __attribute__((ext_vector_type(4))) float f32x4;
typedef __attribute__((ext_vector_type(4))) unsigned short us4;

#define AS1CV(p) ((const __attribute__((address_space(1))) void*)(p))
#define AS3V(p)  ((__attribute__((address_space(3))) void*)(p))

__device__ inline unsigned short f2bf(float f) {
  union { float f; uint32_t u; } c; c.f = f;
  uint32_t u = c.u;
  uint32_t r = (u + 0x7FFFu + ((u >> 16) & 1u)) >> 16;
  return (unsigned short)r;
}

__device__ inline float bf2f(unsigned short s) {
  union { uint32_t u; float f; } c; c.u = ((uint32_t)s) << 16;
  return c.f;
}

__device__ inline unsigned char f2e4m3(float f) {
  __hip_fp8_e4m3 q(f);               // OCP e4m3fn on gfx950
  return (unsigned char)q.__x;
}

// deterministic counter-based uniform in [0,1): murmur3 fmix64 of (phase, idx)
__device__ inline float rng_u(uint32_t phase, uint32_t idx) {
  uint64_t z = (((uint64_t)phase) << 42) | (uint64_t)idx;
  z ^= z >> 33; z *= 0xFF51AFD7ED558CCDULL;
  z ^= z >> 33; z *= 0xC4CEB9FE1A85EC53ULL;
  z ^= z >> 33;
  return (float)(uint32_t)(z >> 40) * (1.0f / 16777216.0f);
}

// ---------------------------------------------------------------------------
// W prep: fp32 -> Wb (bf16, [NH][NV]) for the F-energy GEMMs, plus
// W8 = e4m3(w*64) [NH][NV] and WT8 = e4m3(w*64) [NV][NH] for the fp8 chain.
// ---------------------------------------------------------------------------
__global__ void __launch_bounds__(256) prep_w(const float* __restrict__ w,
                                              unsigned short* __restrict__ Wb,
                                              unsigned char* __restrict__ W8,
                                              unsigned char* __restrict__ WT8)
{
  __shared__ unsigned char t8[64][68];
  const int bi  = blockIdx.x * 64;   // NV offset
  const int bh0 = blockIdx.y * 64;   // NH offset
  const int t   = threadIdx.x;
  const int rr  = t >> 4;            // 0..15
  const int cc  = (t & 15) * 4;      // 0,4,..,60
#pragma unroll
  for (int p = 0; p < 4; ++p) {
    int row = p * 16 + rr;
    const float4 v = *(const float4*)&w[(size_t)(bh0 + row) * NVIS + bi + cc];
    us4 pk; pk.x = f2bf(v.x); pk.y = f2bf(v.y); pk.z = f2bf(v.z); pk.w = f2bf(v.w);
    *(us4*)&Wb[(size_t)(bh0 + row) * NVIS + bi + cc] = pk;
    unsigned char b0 = f2e4m3(v.x * 64.f), b1 = f2e4m3(v.y * 64.f);
    unsigned char b2 = f2e4m3(v.z * 64.f), b3 = f2e4m3(v.w * 64.f);
    uint32_t w8pk = (uint32_t)b0 | ((uint32_t)b1 << 8) |
                    ((uint32_t)b2 << 16) | ((uint32_t)b3 << 24);
    *(uint32_t*)&W8[(size_t)(bh0 + row) * NVIS + bi + cc] = w8pk;
    t8[cc + 0][row] = b0; t8[cc + 1][row] = b1;
    t8[cc + 2][row] = b2; t8[cc + 3][row] = b3;
  }
  __syncthreads();
#pragma unroll
  for (int p = 0; p < 4; ++p) {
    int irow = p * 16 + rr;          // NV-local
    uint32_t o = (uint32_t)t8[irow][cc + 0] | ((uint32_t)t8[irow][cc + 1] << 8) |
                 ((uint32_t)t8[irow][cc + 2] << 16) | ((uint32_t)t8[irow][cc + 3] << 24);
    *(uint32_t*)&WT8[(size_t)(bi + irow) * NHID + bh0 + cc] = o;
  }
}

// x (fp32 0/1) -> bf16 Vb and fp8 V8
__global__ void __launch_bounds__(256) xcvt(const float* __restrict__ x,
                                            unsigned short* __restrict__ Vb,
                                            unsigned char* __restrict__ V8)
{
  int i = blockIdx.x * 256 + threadIdx.x;
  const float4 v = ((const float4*)x)[i];
  us4 pk; pk.x = f2bf(v.x); pk.y = f2bf(v.y); pk.z = f2bf(v.z); pk.w = f2bf(v.w);
  ((us4*)Vb)[i] = pk;
  uint32_t p8 = (uint32_t)f2e4m3(v.x) | ((uint32_t)f2e4m3(v.y) << 8) |
                ((uint32_t)f2e4m3(v.z) << 16) | ((uint32_t)f2e4m3(v.w) << 24);
  ((uint32_t*)V8)[i] = p8;
}

__global__ void __launch_bounds__(256) bvdot(const unsigned short* __restrict__ V,
                                             const float* __restrict__ bv,
                                             float* __restrict__ part)
{
  float local = 0.f;
  for (int v = blockIdx.x * 256 + threadIdx.x; v < T_ROWS * NVIS / 4; v += 256 * 256) {
    int col4 = (v & (NVIS / 4 - 1)) * 4;
    us4 a = ((const us4*)V)[v];
    float4 b = *(const float4*)&bv[col4];
    local += bf2f(a.x) * b.x + bf2f(a.y) * b.y + bf2f(a.z) * b.z + bf2f(a.w) * b.w;
  }
#pragma unroll
  for (int off = 32; off > 0; off >>= 1) local += __shfl_down(local, off, 64);
  __shared__ float red[4];
  if ((threadIdx.x & 63) == 0) red[threadIdx.x >> 6] = local;
  __syncthreads();
  if (threadIdx.x == 0) part[blockIdx.x] = red[0] + red[1] + red[2] + red[3];
}

// ---------------------------------------------------------------------------
// bf16 GEMM (R3 schedule): used only for the two F-energy passes.
// C[M,N] = A[M,K]*B^T, B stored [N][K]. 512 thr = 8 waves (2Mx4N), 16x16x32.
// MODE 1: fpart[block] = sum softplus(z + bias)
// ---------------------------------------------------------------------------
template <int MODE, int BM, int BK>
__global__ void __launch_bounds__(512, 2)
rbm_gemm(const unsigned short* __restrict__ A, int lda,
         const unsigned short* __restrict__ B, int ldb,
         const float* __restrict__ bias,
         unsigned short* __restrict__ C, int ldc,
         float* __restrict__ fpart,
         int kdim, uint32_t phase)
{
  constexpr int MR = BM / 32;
  constexpr int CH = BK / 8;
  constexpr int ABYTES = BM * BK * 2;
  constexpr int BBYTES = 128 * BK * 2;
  constexpr int BUFB = ABYTES + BBYTES;
  constexpr int AJ = ABYTES / 8192;
  constexpr int BJ = BBYTES / 8192;
  constexpr int NL = AJ + BJ;
  constexpr int RSTEP = 512 / CH;
  __shared__ __align__(16) char lds[3 * BUFB];

  const int tid  = threadIdx.x;
  const int lane = tid & 63;
  const int wv   = tid >> 6;
  const int wr   = wv >> 2;
  const int wc   = wv & 3;
  const int lr   = lane & 15;
  const int lq   = lane >> 4;

  const int gx = gridDim.x, gy = gridDim.y;
  const int nb = gx * gy;
  int orig = blockIdx.x + blockIdx.y * gx;
  int id = (orig & 7) * (nb >> 3) + (orig >> 3);
  int tx = id / gy;
  int ty = id - tx * gy;
  const int bm0 = ty * BM;
  const int bn0 = tx * 128;

  const int sRow = tid / CH;
  const int sCol = ((tid % CH) ^ (sRow & (CH - 1))) * 8;
  const unsigned short* gA = A + (size_t)(bm0 + sRow) * lda + sCol;
  const unsigned short* gB = B + (size_t)(bn0 + sRow) * ldb + sCol;

  auto STAGE = [&](int buf, int kt) {
    char* base = lds + buf * BUFB;
    const unsigned short* a0 = gA + (size_t)kt * BK;
    const unsigned short* b0 = gB + (size_t)kt * BK;
#pragma unroll
    for (int j = 0; j < AJ; ++j)
      __builtin_amdgcn_global_load_lds(AS1CV(a0 + (size_t)j * RSTEP * lda),
                                       AS3V(base + (j * 512 + tid) * 16), 16, 0, 0);
    char* bb = base + ABYTES;
#pragma unroll
    for (int j = 0; j < BJ; ++j)
      __builtin_amdgcn_global_load_lds(AS1CV(b0 + (size_t)j * RSTEP * ldb),
                                       AS3V(bb + (j * 512 + tid) * 16), 16, 0, 0);
  };

  f32x4 acc[MR][2];
#pragma unroll
  for (int m = 0; m < MR; ++m)
#pragma unroll
    for (int n = 0; n < 2; ++n) acc[m][n] = (f32x4)0.0f;

  const int nkt = kdim / BK;
  STAGE(0, 0);

  int cur = 0;
  for (int kt = 0; kt < nkt; ++kt) {
    int nxt = (cur == 2) ? 0 : cur + 1;
    if (kt + 1 < nkt) {
      STAGE(nxt, kt + 1);
      if constexpr (NL == 6)      asm volatile("s_waitcnt vmcnt(6)" ::: "memory");
      else if constexpr (NL == 4) asm volatile("s_waitcnt vmcnt(4)" ::: "memory");
      else                        asm volatile("s_waitcnt vmcnt(8)" ::: "memory");
    } else {
      asm volatile("s_waitcnt vmcnt(0)" ::: "memory");
    }
    __builtin_amdgcn_sched_barrier(0);
    __builtin_amdgcn_s_barrier();
    __builtin_amdgcn_sched_barrier(0);

    char* base = lds + cur * BUFB;
    char* bb = base + ABYTES;
#pragma unroll
    for (int ks = 0; ks < BK / 32; ++ks) {
      short8 af[MR], bfr[2];
#pragma unroll
      for (int m = 0; m < MR; ++m) {
        int row = wr * (BM / 2) + m * 16 + lr;
        af[m] = *(const short8*)(base + row * (2 * BK) +
                                 (((ks * 4 + lq) ^ (row & (CH - 1))) * 16));
      }
#pragma unroll
      for (int n = 0; n < 2; ++n) {
        int row = wc * 32 + n * 16 + lr;
        bfr[n] = *(const short8*)(bb + row * (2 * BK) +
                                  (((ks * 4 + lq) ^ (row & (CH - 1))) * 16));
      }
#pragma unroll
      for (int m = 0; m < MR; ++m)
#pragma unroll
        for (int n = 0; n < 2; ++n)
          acc[m][n] = __builtin_amdgcn_mfma_f32_16x16x32_bf16(af[m], bfr[n], acc[m][n], 0, 0, 0);
    }
    cur = nxt;
  }

  {
    float local = 0.0f;
#pragma unroll
    for (int n = 0; n < 2; ++n) {
      int col = bn0 + wc * 32 + n * 16 + lr;
      float bv_ = bias[col];
#pragma unroll
      for (int m = 0; m < MR; ++m) {
#pragma unroll
        for (int j = 0; j < 4; ++j) {
          float z = acc[m][n][j] + bv_;
          local += fmaxf(z, 0.0f) + log1pf(expf(-fabsf(z)));
        }
      }
    }
#pragma unroll
    for (int off = 32; off > 0; off >>= 1) local += __shfl_down(local, off, 64);
    float* red = (float*)lds;
    __syncthreads();
    if (lane == 0) red[wv] = local;
    __syncthreads();
    if (tid == 0)
      fpart[id] = red[0] + red[1] + red[2] + red[3] + red[4] + red[5] + red[6] + red[7];
  }
}

// ---------------------------------------------------------------------------
// fp8 chain GEMM: C = bernoulli(sigmoid(acc/64 + bias)). A [M][K] e4m3 {0,1},
// B [N][K] e4m3 (w*64). BK=128 (128 B/row, CH=8). BM=64 fixed, BN template
// (64 or 128) -> grids of 512 blocks = 2 blocks/CU for latency overlap.
// 512 thr = 8 waves (2Mx4N), wave tile 32 x (BN/4), 16x16x32 fp8 MFMA.
// 3-buffer stage-ahead-1, counted vmcnt (R3 schedule).
// ---------------------------------------------------------------------------
template <int BN>
__global__ void __launch_bounds__(512, 4)
rbm_gemm8(const unsigned char* __restrict__ A, int lda,
          const unsigned char* __restrict__ B, int ldb,
          const float* __restrict__ bias,
          unsigned char* __restrict__ C8,
          unsigned short* __restrict__ Cb, int ldc,
          int kdim, uint32_t phase, int wbf)
{
  constexpr int BM = 64;
  constexpr int BK = 128;
  constexpr int MR = BM / 32;           // 2
  constexpr int NR = BN / 64;           // 1 or 2
  constexpr int ABYTES = BM * BK;       // 8 KB
  constexpr int BBYTES = BN * BK;       // 8 or 16 KB
  constexpr int BUFB = ABYTES + BBYTES;
  constexpr int AJ = ABYTES / 8192;     // 1
  constexpr int BJ = BBYTES / 8192;     // 1 or 2
  constexpr int NL = AJ + BJ;           // 2 or 3
  __shared__ __align__(16) char lds[3 * BUFB];

  const int tid  = threadIdx.x;
  const int lane = tid & 63;
  const int wv   = tid >> 6;
  const int wr   = wv >> 2;             // 0..1 (M)
  const int wc   = wv & 3;              // 0..3 (N)
  const int lr   = lane & 15;
  const int lq   = lane >> 4;           // 0..3

  const int gx = gridDim.x, gy = gridDim.y;
  const int nb = gx * gy;
  int orig = blockIdx.x + blockIdx.y * gx;
  int id = (orig & 7) * (nb >> 3) + (orig >> 3);
  int tx = id / gy;
  int ty = id - tx * gy;
  const int bm0 = ty * BM;
  const int bn0 = tx * BN;

  // staging: chunk L = j*512+tid -> row=L/8, slot=L%8; src chunk = slot^(row&7)
  const int sRow = tid >> 3;            // 0..63
  const int sCol = (((tid & 7) ^ (sRow & 7)) * 16);
  const unsigned char* gA = A + (size_t)(bm0 + sRow) * lda + sCol;
  const unsigned char* gB = B + (size_t)(bn0 + sRow) * ldb + sCol;

  auto STAGE = [&](int buf, int kt) {
    char* base = lds + buf * BUFB;
    const unsigned char* a0 = gA + (size_t)kt * BK;
    const unsigned char* b0 = gB + (size_t)kt * BK;
#pragma unroll
    for (int j = 0; j < AJ; ++j)
      __builtin_amdgcn_global_load_lds(AS1CV(a0 + (size_t)j * 64 * lda),
                                       AS3V(base + (j * 512 + tid) * 16), 16, 0, 0);
    char* bb = base + ABYTES;
#pragma unroll
    for (int j = 0; j < BJ; ++j)
      __builtin_amdgcn_global_load_lds(AS1CV(b0 + (size_t)j * 64 * ldb),
                                       AS3V(bb + (j * 512 + tid) * 16), 16, 0, 0);
  };

  f32x4 acc[MR][NR];
#pragma unroll
  for (int m = 0; m < MR; ++m)
#pragma unroll
    for (int n = 0; n < NR; ++n) acc[m][n] = (f32x4)0.0f;

  const int nkt = kdim / BK;
  STAGE(0, 0);

  int cur = 0;
  for (int kt = 0; kt < nkt; ++kt) {
    int nxt = (cur == 2) ? 0 : cur + 1;
    if (kt + 1 < nkt) {
      STAGE(nxt, kt + 1);
      if constexpr (NL == 2)      asm volatile("s_waitcnt vmcnt(2)" ::: "memory");
      else if constexpr (NL == 3) asm volatile("s_waitcnt vmcnt(3)" ::: "memory");
      else                        asm volatile("s_waitcnt vmcnt(4)" ::: "memory");
    } else {
      asm volatile("s_waitcnt vmcnt(0)" ::: "memory");
    }
    __builtin_amdgcn_sched_barrier(0);
    __builtin_amdgcn_s_barrier();
    __builtin_amdgcn_sched_barrier(0);

    char* base = lds + cur * BUFB;
    char* bb = base + ABYTES;
#pragma unroll
    for (int ks = 0; ks < 4; ++ks) {          // K-slices of 32
      long af[MR], bfr[NR];
      const int cb  = ks * 2 + (lq >> 1);     // 16B chunk index
      const int sub = (lq & 1) * 8;           // 8B within chunk
#pragma unroll
      for (int m = 0; m < MR; ++m) {
        int row = wr * (BM / 2) + m * 16 + lr;
        af[m] = *(const long*)(base + row * BK + ((cb ^ (row & 7)) * 16) + sub);
      }
#pragma unroll
      for (int n = 0; n < NR; ++n) {
        int row = wc * (BN / 4) + n * 16 + lr;
        bfr[n] = *(const long*)(bb + row * BK + ((cb ^ (row & 7)) * 16) + sub);
      }
#pragma unroll
      for (int m = 0; m < MR; ++m)
#pragma unroll
        for (int n = 0; n < NR; ++n)
          acc[m][n] = __builtin_amdgcn_mfma_f32_16x16x32_fp8_fp8(af[m], bfr[n], acc[m][n], 0, 0, 0);
    }
    cur = nxt;
  }

  // epilogue: z = acc/64 + bias; sample; write fp8 (+ optional bf16)
#pragma unroll
  for (int n = 0; n < NR; ++n) {
    int col = bn0 + wc * (BN / 4) + n * 16 + lr;
    float bv_ = bias[col];
#pragma unroll
    for (int m = 0; m < MR; ++m) {
      int row0 = bm0 + wr * (BM / 2) + m * 16 + lq * 4;
#pragma unroll
      for (int j = 0; j < 4; ++j) {
        int row = row0 + j;
        float z = acc[m][n][j] * 0.015625f + bv_;
        float p = 1.0f / (1.0f + __expf(-z));
        float u = rng_u(phase, (uint32_t)(row * ldc + col));
        unsigned char s = (u < p) ? (unsigned char)0x38 : (unsigned char)0; // e4m3 1.0
        C8[(size_t)row * ldc + col] = s;
        if (wbf)
          Cb[(size_t)row * ldc + col] = (u < p) ? (unsigned short)0x3F80 : (unsigned short)0;
      }
    }
  }
}

// cost = (Sv + v.bv - Sx - x.bv) / T, double-precision reduce
__global__ void __launch_bounds__(256) finalize(const float* __restrict__ pFx,
                                                const float* __restrict__ pFv,
                                                const float* __restrict__ pXbv,
                                                const float* __restrict__ pVbv,
                                                float* __restrict__ out)
{
  __shared__ double red[256];
  double local = 0.0;
  int t = threadIdx.x;
  for (int i = t; i < 1024; i += 256) {
    if (i < 256)      local -= (double)pFx[i];
    else if (i < 512) local += (double)pFv[i - 256];
    else if (i < 768) local -= (double)pXbv[i - 512];
    else              local += (double)pVbv[i - 768];
  }
  red[t] = local;
  __syncthreads();
  for (int s = 128; s > 0; s >>= 1) {
    if (t < s) red[t] += red[t + s];
    __syncthreads();
  }
  if (t == 0) out[0] = (float)(red[0] / (double)T_ROWS);
}

extern "C" void kernel_launch(void* const* d_in, const int* in_sizes, int n_in,
                              void* d_out, int out_size, void* d_ws, size_t ws_size,
                              hipStream_t stream)
{
  const float* x  = (const float*)d_in[0];
  const float* w  = (const float*)d_in[1];
  const float* bh = (const float*)d_in[2];
  const float* bv = (const float*)d_in[3];

  char* ws = (char*)d_ws;
  unsigned short* Wb  = (unsigned short*)ws;                            // 16 MB
  unsigned char*  W8  = (unsigned char*)(ws + (size_t)16777216);        //  8 MB
  unsigned char*  WT8 = (unsigned char*)(ws + (size_t)25165824);        //  8 MB
  unsigned short* Vb  = (unsigned short*)(ws + (size_t)33554432);       //  8 MB
  unsigned char*  V8  = (unsigned char*)(ws + (size_t)41943040);        //  4 MB
  unsigned char*  H8  = (unsigned char*)(ws + (size_t)46137344);        //  2 MB
  float* pFx  = (float*)(ws + (size_t)48234496);
  float* pFv  = pFx + 256;
  float* pXbv = pFv + 256;
  float* pVbv = pXbv + 256;

  prep_w<<<dim3(NVIS / 64, NHID / 64), 256, 0, stream>>>(w, Wb, W8, WT8);
  xcvt<<<(T_ROWS * NVIS / 4) / 256, 256, 0, stream>>>(x, Vb, V8);

  // F(x): z = x @ W^T + bh  [1024 x 2048] (bf16, exact path)
  rbm_gemm<1, 64, 128><<<dim3(NHID / 128, T_ROWS / 64), 512, 0, stream>>>(
      Vb, NVIS, Wb, NVIS, bh, nullptr, 0, pFx, NVIS, 0u);
  bvdot<<<256, 256, 0, stream>>>(Vb, bv, pXbv);

  for (int k = 0; k < KGIBBS; ++k) {
    // h ~ Bern(sigmoid(v @ W^T + bh))  [1024 x 2048], fp8, 64x64 tiles, 512 blocks
    rbm_gemm8<64><<<dim3(NHID / 64, T_ROWS / 64), 512, 0, stream>>>(
        V8, NVIS, W8, NVIS, bh, H8, nullptr, NHID, NVIS, (uint32_t)(2 * k), 0);
    // v ~ Bern(sigmoid(h @ W + bv))    [1024 x 4096], fp8, 64x128 tiles, 512 blocks
    rbm_gemm8<128><<<dim3(NVIS / 128, T_ROWS / 64), 512, 0, stream>>>(
        H8, NHID, WT8, NHID, bv, V8, Vb, NVIS, NHID, (uint32_t)(2 * k + 1),
        (k == KGIBBS - 1) ? 1 : 0);
  }

  // F(v_o) (bf16, exact path; Vb written by the last v-GEMM)
  rbm_gemm<1, 64, 128><<<dim3(NHID / 128, T_ROWS / 64), 512, 0, stream>>>(
      Vb, NVIS, Wb, NVIS, bh, nullptr, 0, pFv, NVIS, 0u);
  bvdot<<<256, 256, 0, stream>>>(Vb, bv, pVbv);

  finalize<<<1, 256, 0, stream>>>(pFx, pFv, pXbv, pVbv, (float*)d_out);
}